// Round 1
// baseline (1307.990 us; speedup 1.0000x reference)
//
#include <hip/hip_runtime.h>
#include <hip/hip_bf16.h>

// Bahdanau attention, MI355X.
// Pipeline:
//   1. convert encoder_outputs fp32 -> bf16 into ws (also Wk)
//   2. query = dh @ Wq^T (fp32, small)
//   3. keys GEMM (bf16 MFMA 16x16x32, 128x128 tile, BK=64) with fused
//      epilogue: energy[b,s] += sum_h tanh(q+keys)*v  (atomicAdd)
//   4. softmax over S (with mask)
//   5. context = attn @ enc_bf16 (atomicAdd partials over s-chunks)

#define B_   64
#define S_   1024
#define HID_ 1024
#define ENC_ 2048

typedef unsigned short u16;
typedef float  f32x4  __attribute__((ext_vector_type(4)));
typedef __bf16 bf16x8 __attribute__((ext_vector_type(8)));
typedef u16    u16x8  __attribute__((ext_vector_type(8)));

__device__ __forceinline__ u16 f2bf(float f) {
    unsigned u = __float_as_uint(f);
    u += 0x7FFFu + ((u >> 16) & 1u);   // RNE (inputs are finite)
    return (u16)(u >> 16);
}
__device__ __forceinline__ float bf2f(u16 h) {
    return __uint_as_float(((unsigned)h) << 16);
}

__device__ __forceinline__ void gload16(const void* g, void* l) {
    __builtin_amdgcn_global_load_lds(
        (const __attribute__((address_space(1))) unsigned int*)g,
        (__attribute__((address_space(3))) unsigned int*)l,
        16, 0, 0);
}

// ---------------- fp32 -> bf16 convert (8 elems/thread/iter) ----------------
__global__ __launch_bounds__(256) void cvt_kernel(const float* __restrict__ in,
                                                  u16* __restrict__ out, long n8) {
    long stride = (long)gridDim.x * blockDim.x;
    for (long i = (long)blockIdx.x * blockDim.x + threadIdx.x; i < n8; i += stride) {
        const float4* p = (const float4*)(in + (i << 3));
        float4 a = p[0], c = p[1];
        u16x8 o;
        o[0] = f2bf(a.x); o[1] = f2bf(a.y); o[2] = f2bf(a.z); o[3] = f2bf(a.w);
        o[4] = f2bf(c.x); o[5] = f2bf(c.y); o[6] = f2bf(c.z); o[7] = f2bf(c.w);
        *(u16x8*)(out + (i << 3)) = o;
    }
}

// ---------------- query = dh @ Wq^T  (grid: (4 e-quarters, 64 b)) -----------
__global__ __launch_bounds__(256) void query_kernel(const float* __restrict__ dh,
                                                    const float* __restrict__ Wq,
                                                    float* __restrict__ q) {
    int b = blockIdx.y, eq = blockIdx.x, t = threadIdx.x;
    __shared__ float sdh[256];
    sdh[t] = dh[(b << 10) + (eq << 8) + t];
    __syncthreads();
    float s[4] = {0.f, 0.f, 0.f, 0.f};
    const float* wbase = Wq + (eq << 8);
    for (int e = 0; e < 256; e += 4) {
        float4 d = *(const float4*)(sdh + e);
        #pragma unroll
        for (int r = 0; r < 4; ++r) {
            int h = t + (r << 8);
            float4 wv = *(const float4*)(wbase + (size_t)h * HID_ + e);
            s[r] += wv.x * d.x + wv.y * d.y + wv.z * d.z + wv.w * d.w;
        }
    }
    #pragma unroll
    for (int r = 0; r < 4; ++r) atomicAdd(&q[(b << 10) + t + (r << 8)], s[r]);
}

// ---------------- keys GEMM + fused energy epilogue -------------------------
// A = enc_bf [65536][2048], Bw = wk_bf [1024][2048] (both row-major, K contig)
// 128x128 tile, BK=64, 4 waves (2x2 of 64x64), mfma_f32_16x16x32_bf16.
// LDS: A[128][64] + B[128][64] bf16, XOR-swizzled: byte ^= (row&7)<<4.
// global_load_lds is linear-dest, so the swizzle is applied to the SOURCE
// address (rule 21) and to the ds_read address.
__global__ __launch_bounds__(256) void keys_gemm(const u16* __restrict__ A,
                                                 const u16* __restrict__ Bw,
                                                 const float* __restrict__ q,
                                                 const float* __restrict__ v,
                                                 float* __restrict__ energy) {
    __shared__ u16 lds[16384];                       // 32 KiB: A then B
    int bid = blockIdx.x;
    int swz = ((bid & 7) << 9) + (bid >> 3);         // XCD-aware (4096 % 8 == 0)
    int mt = swz >> 3, nt = swz & 7;
    int t = threadIdx.x;
    int w = t >> 6, l = t & 63;
    int lr = l >> 3, lc = l & 7;
    int srcsw = ((lc ^ lr) << 3);                    // swizzled source elem off
    const u16* Abase = A + ((size_t)(mt << 7)) * ENC_;
    const u16* Bbase = Bw + ((size_t)(nt << 7)) * ENC_;
    char* ldsA = (char*)lds;
    char* ldsB = (char*)lds + 16384;
    int srow = (w << 5) + lr;                        // + p*8
    int dstoff = (w << 12) + (l << 4);               // + p*1024
    int lhi = l >> 4, llo = l & 15;
    int wm = w >> 1, wn = w & 1;
    int asw = (llo & 7) << 4;                        // read-side XOR
    f32x4 acc[4][4] = {};

    for (int kt = 0; kt < ENC_; kt += 64) {
        #pragma unroll
        for (int p = 0; p < 4; ++p) {
            gload16(Abase + (size_t)(srow + (p << 3)) * ENC_ + kt + srcsw,
                    ldsA + dstoff + (p << 10));
            gload16(Bbase + (size_t)(srow + (p << 3)) * ENC_ + kt + srcsw,
                    ldsB + dstoff + (p << 10));
        }
        __syncthreads();
        #pragma unroll
        for (int kk = 0; kk < 64; kk += 32) {
            bf16x8 af[4], bf[4];
            int cb = ((kk << 1) + (lhi << 4)) ^ asw;
            #pragma unroll
            for (int i = 0; i < 4; ++i)
                af[i] = *(const bf16x8*)(ldsA + (((wm << 6) + (i << 4) + llo) << 7) + cb);
            #pragma unroll
            for (int j = 0; j < 4; ++j)
                bf[j] = *(const bf16x8*)(ldsB + (((wn << 6) + (j << 4) + llo) << 7) + cb);
            #pragma unroll
            for (int i = 0; i < 4; ++i)
                #pragma unroll
                for (int j = 0; j < 4; ++j)
                    acc[i][j] = __builtin_amdgcn_mfma_f32_16x16x32_bf16(
                        af[i], bf[j], acc[i][j], 0, 0, 0);
        }
        __syncthreads();
    }

    // epilogue: energy[m] += sum_h tanh(q[b,h] + keys[m,h]) * v[h]
    int b = mt >> 3;                                  // 8 m-tiles per batch row
    float qv[4], vv[4];
    #pragma unroll
    for (int j = 0; j < 4; ++j) {
        int h = (nt << 7) + (wn << 6) + (j << 4) + llo;
        qv[j] = q[(b << 10) + h];
        vv[j] = v[h];
    }
    #pragma unroll
    for (int i = 0; i < 4; ++i) {
        #pragma unroll
        for (int r = 0; r < 4; ++r) {
            float part = 0.f;
            #pragma unroll
            for (int j = 0; j < 4; ++j)
                part += tanhf(qv[j] + acc[i][j][r]) * vv[j];
            part += __shfl_down(part, 8);
            part += __shfl_down(part, 4);
            part += __shfl_down(part, 2);
            part += __shfl_down(part, 1);
            if (llo == 0) {
                int m = (mt << 7) + (wm << 6) + (i << 4) + (lhi << 2) + r;
                atomicAdd(&energy[m], part);
            }
        }
    }
}

// ---------------- softmax over S (one block per b) --------------------------
__global__ __launch_bounds__(256) void softmax_kernel(const float* __restrict__ energy,
                                                      const int* __restrict__ mask,
                                                      float* __restrict__ attn) {
    int b = blockIdx.x, t = threadIdx.x;
    int w = t >> 6, l = t & 63;
    __shared__ float rmax[4], rsum[4];
    float4 e = *(const float4*)(energy + (b << 10) + (t << 2));
    int4 mk = *(const int4*)(mask + (b << 10) + (t << 2));
    if (mk.x == 0) e.x = -1e10f;
    if (mk.y == 0) e.y = -1e10f;
    if (mk.z == 0) e.z = -1e10f;
    if (mk.w == 0) e.w = -1e10f;
    float mx = fmaxf(fmaxf(e.x, e.y), fmaxf(e.z, e.w));
    for (int off = 32; off >= 1; off >>= 1) mx = fmaxf(mx, __shfl_xor(mx, off));
    if (l == 0) rmax[w] = mx;
    __syncthreads();
    mx = fmaxf(fmaxf(rmax[0], rmax[1]), fmaxf(rmax[2], rmax[3]));
    float4 ex;
    ex.x = expf(e.x - mx); ex.y = expf(e.y - mx);
    ex.z = expf(e.z - mx); ex.w = expf(e.w - mx);
    float sm = ex.x + ex.y + ex.z + ex.w;
    for (int off = 32; off >= 1; off >>= 1) sm += __shfl_xor(sm, off);
    if (l == 0) rsum[w] = sm;
    __syncthreads();
    sm = rsum[0] + rsum[1] + rsum[2] + rsum[3];
    float inv = 1.0f / sm;
    ex.x *= inv; ex.y *= inv; ex.z *= inv; ex.w *= inv;
    *(float4*)(attn + (b << 10) + (t << 2)) = ex;
}

// ---------------- context = attn @ enc (grid: (8 s-chunks, 64 b)) -----------
__global__ __launch_bounds__(256) void context_kernel(const u16* __restrict__ enc_bf,
                                                      const float* __restrict__ attn,
                                                      float* __restrict__ ctx) {
    int b = blockIdx.y;
    int s0 = blockIdx.x << 7;
    int t = threadIdx.x;
    int e0 = t << 3;
    float acc[8] = {};
    const u16* base = enc_bf + ((size_t)((b << 10) + s0)) * ENC_ + e0;
    const float* wp = attn + (b << 10) + s0;
    for (int s = 0; s < 128; ++s) {
        float wgt = wp[s];
        u16x8 u = *(const u16x8*)(base + (size_t)s * ENC_);
        #pragma unroll
        for (int k = 0; k < 8; ++k) acc[k] += wgt * bf2f(u[k]);
    }
    float* cb = ctx + (b << 11) + e0;
    #pragma unroll
    for (int k = 0; k < 8; ++k) atomicAdd(&cb[k], acc[k]);
}

extern "C" void kernel_launch(void* const* d_in, const int* in_sizes, int n_in,
                              void* d_out, int out_size, void* d_ws, size_t ws_size,
                              hipStream_t stream) {
    const float* dh   = (const float*)d_in[0];   // [64,1024]
    const float* enc  = (const float*)d_in[1];   // [64,1024,2048]
    const int*   mask = (const int*)d_in[2];     // [64,1024]
    const float* Wq   = (const float*)d_in[3];   // [1024,1024]
    const float* Wk   = (const float*)d_in[4];   // [1024,2048]
    const float* v    = (const float*)d_in[5];   // [1024]
    float* out  = (float*)d_out;
    float* ctx  = out;                 // [64,2048]
    float* attn = out + B_ * ENC_;     // [64,1024]

    const size_t ENC_BF_BYTES = (size_t)B_ * S_ * ENC_ * 2;   // 268435456
    const size_t WK_BF_BYTES  = (size_t)HID_ * ENC_ * 2;      // 4194304
    const size_t Q_BYTES      = (size_t)B_ * HID_ * 4;        // 262144
    const size_t E_BYTES      = (size_t)B_ * S_ * 4;          // 262144
    if (ws_size < ENC_BF_BYTES + WK_BF_BYTES + Q_BYTES + E_BYTES) return;

    char* ws = (char*)d_ws;
    u16*   enc_bf = (u16*)ws;
    u16*   wk_bf  = (u16*)(ws + ENC_BF_BYTES);
    float* qbuf   = (float*)(ws + ENC_BF_BYTES + WK_BF_BYTES);
    float* energy = (float*)(ws + ENC_BF_BYTES + WK_BF_BYTES + Q_BYTES);

    hipMemsetAsync(qbuf, 0, Q_BYTES, stream);
    hipMemsetAsync(energy, 0, E_BYTES, stream);
    hipMemsetAsync(d_out, 0, (size_t)out_size * 4, stream);

    cvt_kernel<<<2048, 256, 0, stream>>>(enc, enc_bf, (long)((size_t)B_ * S_ * ENC_ / 8));
    cvt_kernel<<<128, 256, 0, stream>>>(Wk, wk_bf, (long)((size_t)HID_ * ENC_ / 8));
    query_kernel<<<dim3(4, B_), 256, 0, stream>>>(dh, Wq, qbuf);
    keys_gemm<<<4096, 256, 0, stream>>>(enc_bf, wk_bf, qbuf, v, energy);
    softmax_kernel<<<B_, 256, 0, stream>>>(energy, mask, attn);
    context_kernel<<<dim3(8, B_), 256, 0, stream>>>(enc_bf, attn, ctx);
}

// Round 2
// 1125.479 us; speedup vs baseline: 1.1622x; 1.1622x over previous
//
#include <hip/hip_runtime.h>
#include <hip/hip_bf16.h>

// Bahdanau attention, MI355X.
//   1. cvt encoder_outputs fp32 -> bf16 (ws), cvt Wk
//   2. query = dh @ Wq^T (fp32, wave-per-row coalesced)
//   3. keys GEMM: 256x256 tile, BK=64, 8 waves, 8-phase schedule with
//      counted vmcnt(4), XOR-swizzled LDS, global_load_lds w=16, setprio.
//      Fused epilogue: energy[b,s] += sum_h tanh(q+keys)*v (atomicAdd)
//   4. softmax over S (with mask)
//   5. context = attn @ enc_bf16

#define B_   64
#define S_   1024
#define HID_ 1024
#define ENC_ 2048

typedef unsigned short u16;
typedef float  f32x4  __attribute__((ext_vector_type(4)));
typedef __bf16 bf16x8 __attribute__((ext_vector_type(8)));
typedef u16    u16x8  __attribute__((ext_vector_type(8)));

__device__ __forceinline__ u16 f2bf(float f) {
    unsigned u = __float_as_uint(f);
    u += 0x7FFFu + ((u >> 16) & 1u);   // RNE (inputs finite)
    return (u16)(u >> 16);
}
__device__ __forceinline__ float bf2f(u16 h) {
    return __uint_as_float(((unsigned)h) << 16);
}

__device__ __forceinline__ void gload16(const void* g, void* l) {
    __builtin_amdgcn_global_load_lds(
        (const __attribute__((address_space(1))) unsigned int*)g,
        (__attribute__((address_space(3))) unsigned int*)l,
        16, 0, 0);
}

#define BAR() __builtin_amdgcn_s_barrier()
#define LG0() do { asm volatile("s_waitcnt lgkmcnt(0)" ::: "memory"); \
                   __builtin_amdgcn_sched_barrier(0); } while (0)
#define VM4() asm volatile("s_waitcnt vmcnt(4)" ::: "memory")

// ---------------- fp32 -> bf16 convert ----------------
__global__ __launch_bounds__(256) void cvt_kernel(const float* __restrict__ in,
                                                  u16* __restrict__ out, long n8) {
    long stride = (long)gridDim.x * blockDim.x;
    for (long i = (long)blockIdx.x * blockDim.x + threadIdx.x; i < n8; i += stride) {
        const float4* p = (const float4*)(in + (i << 3));
        float4 a = p[0], c = p[1];
        u16x8 o;
        o[0] = f2bf(a.x); o[1] = f2bf(a.y); o[2] = f2bf(a.z); o[3] = f2bf(a.w);
        o[4] = f2bf(c.x); o[5] = f2bf(c.y); o[6] = f2bf(c.z); o[7] = f2bf(c.w);
        *(u16x8*)(out + (i << 3)) = o;
    }
}

// ---------------- query: one wave per h row, coalesced --------------------
__global__ __launch_bounds__(256) void query_kernel(const float* __restrict__ dh,
                                                    const float* __restrict__ Wq,
                                                    float* __restrict__ q) {
    int w = threadIdx.x >> 6, l = threadIdx.x & 63;
    int h = (blockIdx.x << 2) + w;                   // 256 blocks x 4 waves
    float4 wv[4];
    const float* wrow = Wq + (size_t)h * HID_;
    #pragma unroll
    for (int it = 0; it < 4; ++it) wv[it] = *(const float4*)(wrow + (it << 8) + (l << 2));
    for (int b = 0; b < 64; ++b) {
        const float* dr = dh + (b << 10);
        float s = 0.f;
        #pragma unroll
        for (int it = 0; it < 4; ++it) {
            float4 d = *(const float4*)(dr + (it << 8) + (l << 2));
            s += wv[it].x * d.x + wv[it].y * d.y + wv[it].z * d.z + wv[it].w * d.w;
        }
        #pragma unroll
        for (int off = 32; off >= 1; off >>= 1) s += __shfl_xor(s, off);
        if (l == 0) q[(b << 10) + h] = s;
    }
}

// ---------------- keys GEMM, 8-phase 256^2 template -----------------------
// A = enc_bf [65536][2048], Bw = wk_bf [1024][2048], K contiguous.
// LDS 128 KiB: buf0 (even K-tiles) / buf1 (odd): [A0|A1|B0|B1] halves of
// 128x64 bf16 = 16 KiB each.  Swizzle: granule g at row r lives at linear
// idx r*8 + (g^(r&7)); staged via inverse-swizzled global source.
__global__ __launch_bounds__(512, 2) void keys_gemm(const u16* __restrict__ A,
                                                    const u16* __restrict__ Bw,
                                                    const float* __restrict__ q,
                                                    const float* __restrict__ v,
                                                    float* __restrict__ energy) {
    __shared__ char smem[131072];
    int bid = blockIdx.x;
    int wg = ((bid & 7) << 7) + (bid >> 3);          // XCD swizzle, 1024%8==0
    int mt = wg >> 2, nt = wg & 3;
    int t = threadIdx.x;
    int w = t >> 6, l = t & 63;
    int wm = w >> 2, wn = w & 3;                     // 2M x 4N wave grid
    int lhi = l >> 4, llo = l & 15;
    const u16* Apan = A  + ((size_t)mt << 8) * ENC_;
    const u16* Bpan = Bw + ((size_t)nt << 8) * ENC_;

    // per-thread staging constants: idx_p = p*512 + t
    int r0 = t >> 3, g0 = t & 7;
    int r1 = (512 + t) >> 3, g1 = t & 7;
    int c0 = (g0 ^ (r0 & 7)) << 3;                   // src col elems
    int c1 = (g1 ^ (r1 & 7)) << 3;

    // frag read bases
    char* aHalf = smem + wm * 16384;                 // + buf*65536
    char* bHalf = smem + 32768 + (wn >> 1) * 16384;
    int bRowO = (wn & 1) << 6;
    int axor = (llo & 7) << 4;

    f32x4 acc[8][4] = {};
    bf16x8 a[4][2], b01[2][2], b23[2][2];

    auto STAGE = [&](const u16* pan, int rowBase, int kt, int ldsOfs) {
        gload16(pan + (size_t)(rowBase + r0) * ENC_ + kt + c0, smem + ldsOfs + (t << 4));
        gload16(pan + (size_t)(rowBase + r1) * ENC_ + kt + c1, smem + ldsOfs + 8192 + (t << 4));
    };
    auto LDA = [&](int bufofs, int ibase) {
        #pragma unroll
        for (int ii = 0; ii < 4; ++ii)
            #pragma unroll
            for (int k = 0; k < 2; ++k)
                a[ii][k] = *(const bf16x8*)(aHalf + bufofs +
                    ((llo + ((ibase + ii) << 4)) << 7) + ((((k << 2) + lhi) << 4) ^ axor));
    };
    auto LDB = [&](bf16x8 (&bb)[2][2], int bufofs, int jbase) {
        #pragma unroll
        for (int j = 0; j < 2; ++j)
            #pragma unroll
            for (int k = 0; k < 2; ++k)
                bb[j][k] = *(const bf16x8*)(bHalf + bufofs +
                    ((bRowO + llo + ((jbase + j) << 4)) << 7) + ((((k << 2) + lhi) << 4) ^ axor));
    };
    auto MM = [&](bf16x8 (&bb)[2][2], int ibase, int jbase) {
        __builtin_amdgcn_s_setprio(1);
        #pragma unroll
        for (int ii = 0; ii < 4; ++ii)
            #pragma unroll
            for (int j = 0; j < 2; ++j)
                #pragma unroll
                for (int k = 0; k < 2; ++k)
                    acc[ibase + ii][jbase + j] = __builtin_amdgcn_mfma_f32_16x16x32_bf16(
                        a[ii][k], bb[j][k], acc[ibase + ii][jbase + j], 0, 0, 0);
        __builtin_amdgcn_s_setprio(0);
    };

    // prologue: tile0 full (buf0) + tile1 B halves (buf1); vmcnt(4)
    STAGE(Apan, 0,   0,  0);
    STAGE(Apan, 128, 0,  16384);
    STAGE(Bpan, 0,   0,  32768);
    STAGE(Bpan, 128, 0,  49152);
    STAGE(Bpan, 0,   64, 65536 + 32768);
    STAGE(Bpan, 128, 64, 65536 + 49152);
    VM4();
    BAR();

    #pragma unroll 1
    for (int u = 0; u < 16; ++u) {
        int ktA = u << 7, ktB = ktA + 64;
        int ks2 = ktA + 128; if (ks2 >= ENC_) ks2 -= 128;   // tile 2u+2 (clamped)
        int ks3 = ktA + 192; if (ks3 >= ENC_) ks3 -= 128;   // tile 2u+3 (clamped)

        // P1
        LDA(0, 0); LDB(b01, 0, 0);
        STAGE(Apan, 0, ktB, 65536);
        BAR(); LG0(); MM(b01, 0, 0); BAR();
        // P2
        LDB(b23, 0, 2);
        STAGE(Apan, 128, ktB, 65536 + 16384);
        BAR(); LG0(); MM(b23, 0, 2); BAR();
        // P3
        LDA(0, 4);
        STAGE(Bpan, 0, ks2, 32768);
        BAR(); LG0(); MM(b23, 4, 2); BAR();
        // P4
        STAGE(Bpan, 128, ks2, 49152);
        VM4();
        BAR(); LG0(); MM(b01, 4, 0); BAR();
        // P5
        LDA(65536, 0); LDB(b01, 65536, 0);
        STAGE(Apan, 0, ks2, 0);
        BAR(); LG0(); MM(b01, 0, 0); BAR();
        // P6
        LDB(b23, 65536, 2);
        STAGE(Apan, 128, ks2, 16384);
        BAR(); LG0(); MM(b23, 0, 2); BAR();
        // P7
        LDA(65536, 4);
        STAGE(Bpan, 0, ks3, 65536 + 32768);
        BAR(); LG0(); MM(b23, 4, 2); BAR();
        // P8
        STAGE(Bpan, 128, ks3, 65536 + 49152);
        VM4();
        BAR(); LG0(); MM(b01, 4, 0); BAR();
    }

    // epilogue: energy[m] += sum_h tanh(q[b,h] + keys[m,h]) * v[h]
    int b = mt >> 2;
    float qv[4], vv[4];
    #pragma unroll
    for (int j = 0; j < 4; ++j) {
        int h = (nt << 8) + (wn << 6) + (j << 4) + llo;
        qv[j] = q[(b << 10) + h];
        vv[j] = v[h];
    }
    #pragma unroll
    for (int i = 0; i < 8; ++i) {
        #pragma unroll
        for (int r = 0; r < 4; ++r) {
            float part = 0.f;
            #pragma unroll
            for (int j = 0; j < 4; ++j)
                part += tanhf(qv[j] + acc[i][j][r]) * vv[j];
            part += __shfl_down(part, 8);
            part += __shfl_down(part, 4);
            part += __shfl_down(part, 2);
            part += __shfl_down(part, 1);
            if (llo == 0) {
                int m = (mt << 8) + (wm << 7) + (i << 4) + (lhi << 2) + r;
                atomicAdd(&energy[m], part);
            }
        }
    }
}

// ---------------- softmax over S (one block per b) ------------------------
__global__ __launch_bounds__(256) void softmax_kernel(const float* __restrict__ energy,
                                                      const int* __restrict__ mask,
                                                      float* __restrict__ attn) {
    int b = blockIdx.x, t = threadIdx.x;
    int w = t >> 6, l = t & 63;
    __shared__ float rmax[4], rsum[4];
    float4 e = *(const float4*)(energy + (b << 10) + (t << 2));
    int4 mk = *(const int4*)(mask + (b << 10) + (t << 2));
    if (mk.x == 0) e.x = -1e10f;
    if (mk.y == 0) e.y = -1e10f;
    if (mk.z == 0) e.z = -1e10f;
    if (mk.w == 0) e.w = -1e10f;
    float mx = fmaxf(fmaxf(e.x, e.y), fmaxf(e.z, e.w));
    for (int off = 32; off >= 1; off >>= 1) mx = fmaxf(mx, __shfl_xor(mx, off));
    if (l == 0) rmax[w] = mx;
    __syncthreads();
    mx = fmaxf(fmaxf(rmax[0], rmax[1]), fmaxf(rmax[2], rmax[3]));
    float4 ex;
    ex.x = expf(e.x - mx); ex.y = expf(e.y - mx);
    ex.z = expf(e.z - mx); ex.w = expf(e.w - mx);
    float sm = ex.x + ex.y + ex.z + ex.w;
    for (int off = 32; off >= 1; off >>= 1) sm += __shfl_xor(sm, off);
    if (l == 0) rsum[w] = sm;
    __syncthreads();
    sm = rsum[0] + rsum[1] + rsum[2] + rsum[3];
    float inv = 1.0f / sm;
    ex.x *= inv; ex.y *= inv; ex.z *= inv; ex.w *= inv;
    *(float4*)(attn + (b << 10) + (t << 2)) = ex;
}

// ---------------- context = attn @ enc ------------------------------------
__global__ __launch_bounds__(256) void context_kernel(const u16* __restrict__ enc_bf,
                                                      const float* __restrict__ attn,
                                                      float* __restrict__ ctx) {
    int b = blockIdx.y;
    int s0 = blockIdx.x << 7;
    int t = threadIdx.x;
    int e0 = t << 3;
    float acc[8] = {};
    const u16* base = enc_bf + ((size_t)((b << 10) + s0)) * ENC_ + e0;
    const float* wp = attn + (b << 10) + s0;
    for (int s = 0; s < 128; ++s) {
        float wgt = wp[s];
        u16x8 u = *(const u16x8*)(base + (size_t)s * ENC_);
        #pragma unroll
        for (int k = 0; k < 8; ++k) acc[k] += wgt * bf2f(u[k]);
    }
    float* cb = ctx + (b << 11) + e0;
    #pragma unroll
    for (int k = 0; k < 8; ++k) atomicAdd(&cb[k], acc[k]);
}

extern "C" void kernel_launch(void* const* d_in, const int* in_sizes, int n_in,
                              void* d_out, int out_size, void* d_ws, size_t ws_size,
                              hipStream_t stream) {
    const float* dh   = (const float*)d_in[0];
    const float* enc  = (const float*)d_in[1];
    const int*   mask = (const int*)d_in[2];
    const float* Wq   = (const float*)d_in[3];
    const float* Wk   = (const float*)d_in[4];
    const float* v    = (const float*)d_in[5];
    float* out  = (float*)d_out;
    float* ctx  = out;                 // [64,2048]
    float* attn = out + B_ * ENC_;     // [64,1024]

    const size_t ENC_BF_BYTES = (size_t)B_ * S_ * ENC_ * 2;
    const size_t WK_BF_BYTES  = (size_t)HID_ * ENC_ * 2;
    const size_t Q_BYTES      = (size_t)B_ * HID_ * 4;
    const size_t E_BYTES      = (size_t)B_ * S_ * 4;
    if (ws_size < ENC_BF_BYTES + WK_BF_BYTES + Q_BYTES + E_BYTES) return;

    char* ws = (char*)d_ws;
    u16*   enc_bf = (u16*)ws;
    u16*   wk_bf  = (u16*)(ws + ENC_BF_BYTES);
    float* qbuf   = (float*)(ws + ENC_BF_BYTES + WK_BF_BYTES);
    float* energy = (float*)(ws + ENC_BF_BYTES + WK_BF_BYTES + Q_BYTES);

    hipMemsetAsync(energy, 0, E_BYTES, stream);
    hipMemsetAsync(d_out, 0, (size_t)out_size * 4, stream);

    cvt_kernel<<<2048, 256, 0, stream>>>(enc, enc_bf, (long)((size_t)B_ * S_ * ENC_ / 8));
    cvt_kernel<<<128, 256, 0, stream>>>(Wk, wk_bf, (long)((size_t)HID_ * ENC_ / 8));
    query_kernel<<<256, 256, 0, stream>>>(dh, Wq, qbuf);
    keys_gemm<<<1024, 512, 0, stream>>>(enc_bf, wk_bf, qbuf, v, energy);
    softmax_kernel<<<B_, 256, 0, stream>>>(energy, mask, attn);
    context_kernel<<<dim3(8, B_), 256, 0, stream>>>(enc_bf, attn, ctx);
}